// Round 7
// baseline (362.675 us; speedup 1.0000x reference)
//
#include <hip/hip_runtime.h>
#include <hip/hip_fp16.h>
#include <math.h>

#define N_NODES 100000
#define N_EDGES 1600000
#define IN_CH   64
#define GCN_CH  64
#define OUT_CH  32
#define MAXDEG  48   // P(Poisson(16) >= 48) * 100k ~ 1e-5; guarded in fill

// ---------------------------------------------------------------------------
// 1) ELL fill: cursor atomic IS the histogram. One atomic + one 8B store/edge.
//    ell[c*MAXDEG + k] = (src, edge_weight)
// ---------------------------------------------------------------------------
__global__ void fill_ell_kernel(const int* __restrict__ row, const int* __restrict__ col,
                                const float* __restrict__ ew,
                                int* __restrict__ cnt, int2* __restrict__ ell) {
    int e = blockIdx.x * blockDim.x + threadIdx.x;
    if (e >= N_EDGES) return;
    int r = row[e], c = col[e];
    int k = atomicAdd(&cnt[c], 1);
    if (k < MAXDEG)
        ell[(size_t)c * MAXDEG + k] = make_int2(r, __float_as_int(ew[e]));
}

// ---------------------------------------------------------------------------
// 2) dis[i] = rsqrt(sum of row weights + 1).  16 lanes per node.
// ---------------------------------------------------------------------------
__global__ void dis_ell_kernel(const int* __restrict__ cnt, const int2* __restrict__ ell,
                               float* __restrict__ dis) {
    int t = threadIdx.x;
    int node = blockIdx.x * 16 + (t >> 4);
    if (node >= N_NODES) return;
    int l = t & 15;
    int deg = cnt[node];
    const int2* erow = ell + (size_t)node * MAXDEG;
    float sum = 0.f;
    for (int k = l; k < deg; k += 16)
        sum += __int_as_float(erow[k].y);
    sum += __shfl_xor(sum, 1, 64);
    sum += __shfl_xor(sum, 2, 64);
    sum += __shfl_xor(sum, 4, 64);
    sum += __shfl_xor(sum, 8, 64);
    if (l == 0) dis[node] = rsqrtf(sum + 1.0f);
}

// ---------------------------------------------------------------------------
// 3) dense GEMM  Yh[N,64] = fp16( X[N,64] @ W[64,64] )
// ---------------------------------------------------------------------------
__global__ void gemm64_f16_kernel(const float* __restrict__ X, const float* __restrict__ W,
                                  __half* __restrict__ Y, int nrows) {
    __shared__ float4 Ws[64][16];   // Ws[k][q] = W[k][4q..4q+3]
    int t = threadIdx.x;
    for (int i = t; i < 64 * 16; i += 256)
        ((float4*)Ws)[i] = ((const float4*)W)[i];
    __syncthreads();

    int q   = t & 15;
    int sub = t >> 4;               // 16 rows per block
    int row = blockIdx.x * 16 + sub;
    if (row >= nrows) return;
    const float4* xr = (const float4*)(X + (size_t)row * 64);
    float4 acc = {0.f, 0.f, 0.f, 0.f};
#pragma unroll
    for (int k4 = 0; k4 < 16; ++k4) {
        float4 xv = xr[k4];
#pragma unroll
        for (int j = 0; j < 4; ++j) {
            float xs = (j == 0) ? xv.x : (j == 1) ? xv.y : (j == 2) ? xv.z : xv.w;
            float4 wv = Ws[k4 * 4 + j][q];
            acc.x = fmaf(xs, wv.x, acc.x);
            acc.y = fmaf(xs, wv.y, acc.y);
            acc.z = fmaf(xs, wv.z, acc.z);
            acc.w = fmaf(xs, wv.w, acc.w);
        }
    }
    union { __half2 h[2]; float2 f; } u;
    u.h[0] = __floats2half2_rn(acc.x, acc.y);
    u.h[1] = __floats2half2_rn(acc.z, acc.w);
    *(float2*)(Y + (size_t)row * 64 + q * 4) = u.f;
}

// ---------------------------------------------------------------------------
// helper: load 8 fp16 channels (16 B) and fma into 8 fp32 accumulators
// ---------------------------------------------------------------------------
__device__ inline void fma8_f16(const __half* p, float nv, float* acc) {
    float4 raw = *(const float4*)p;
    const __half2* hp = (const __half2*)&raw;
#pragma unroll
    for (int i = 0; i < 4; ++i) {
        acc[2 * i + 0] = fmaf(nv, __low2float(hp[i]),  acc[2 * i + 0]);
        acc[2 * i + 1] = fmaf(nv, __high2float(hp[i]), acc[2 * i + 1]);
    }
}

// helper: shared epilogue — h[i] = relu(dc*(acc[i] + dc*x_self[i]) + b[i])
__device__ inline void make_h(const float* acc, const __half* xself_p,
                              const float* b, int q, float dc, float* h) {
    float4 raw = *(const float4*)xself_p;
    const __half2* hp = (const __half2*)&raw;
    float4 b0 = *(const float4*)(b + q * 8);
    float4 b1 = *(const float4*)(b + q * 8 + 4);
    float xs[8] = {__low2float(hp[0]), __high2float(hp[0]),
                   __low2float(hp[1]), __high2float(hp[1]),
                   __low2float(hp[2]), __high2float(hp[2]),
                   __low2float(hp[3]), __high2float(hp[3])};
    float bb[8] = {b0.x, b0.y, b0.z, b0.w, b1.x, b1.y, b1.z, b1.w};
#pragma unroll
    for (int i = 0; i < 8; ++i) {
        float tmp = fmaf(dc, xs[i], acc[i]);      // acc + dc * x_self
        h[i] = fmaxf(fmaf(dc, tmp, bb[i]), 0.f);  // dc*(...) + b, relu
    }
}

// ---------------------------------------------------------------------------
// 4) gather_mid: layer-1 aggregate + self + b1 + relu  ->  h, then h @ W2
//    (matvec via shfl broadcasts, W2 in LDS)  -> XW2h (fp16)
//    One wave per node. lane = (edge-group g = lane>>3) x (channel-oct q = lane&7)
//    acc accumulates  sum( dis[r]*ew * x[r] );  dis[c] folded out of the loop.
// ---------------------------------------------------------------------------
__global__ void gather_mid_kernel(const int* __restrict__ cnt, const int2* __restrict__ ell,
                                  const __half* __restrict__ XWh,
                                  const float* __restrict__ dis, const float* __restrict__ b,
                                  const float* __restrict__ W2,
                                  __half* __restrict__ XW2h) {
    __shared__ float Ws[64][64];              // W2[k][j], 16 KB
    {
        int t = threadIdx.x;
        for (int i = t; i < 64 * 64 / 4; i += 256)
            ((float4*)Ws)[i] = ((const float4*)W2)[i];
        __syncthreads();
    }

    int node = blockIdx.x * 4 + (threadIdx.x >> 6);
    if (node >= N_NODES) return;
    int lane = threadIdx.x & 63;
    int g = lane >> 3;          // edge group 0..7
    int q = lane & 7;           // channel oct
    int deg = cnt[node];
    const int2* erow = ell + (size_t)node * MAXDEG;

    float acc[8] = {0.f, 0.f, 0.f, 0.f, 0.f, 0.f, 0.f, 0.f};
    for (int s = g; s < deg; s += 8) {
        int2  rec = erow[s];
        float nv  = dis[rec.x] * __int_as_float(rec.y);   // dis[r] * ew
        fma8_f16(XWh + (size_t)rec.x * 64 + q * 8, nv, acc);
    }
#pragma unroll
    for (int m = 8; m <= 32; m <<= 1)
#pragma unroll
        for (int i = 0; i < 8; ++i)
            acc[i] += __shfl_xor(acc[i], m, 64);

    float dc = dis[node];
    float h[8];
    make_h(acc, XWh + (size_t)node * 64 + q * 8, b, q, dc, h);

    // xw2[lane] = sum_k h[k] * W2[k][lane]  (shfl-broadcast matvec)
    float outv = 0.f;
#pragma unroll
    for (int qp = 0; qp < 8; ++qp)
#pragma unroll
        for (int i = 0; i < 8; ++i) {
            float hv = __shfl(h[i], qp, 64);
            outv = fmaf(hv, Ws[qp * 8 + i][lane], outv);
        }
    XW2h[(size_t)node * 64 + lane] = __float2half(outv);
}

// ---------------------------------------------------------------------------
// 5) gather_out: layer-2 aggregate + self + b2 + relu -> h2, then
//    tanh(h2 @ Wout + bout) -> OUT
// ---------------------------------------------------------------------------
__global__ void gather_out_kernel(const int* __restrict__ cnt, const int2* __restrict__ ell,
                                  const __half* __restrict__ XWh,
                                  const float* __restrict__ dis, const float* __restrict__ b,
                                  const float* __restrict__ Wout, const float* __restrict__ bout,
                                  float* __restrict__ OUT) {
    __shared__ float Ws[64][OUT_CH];          // Wout[k][j], 8 KB
    {
        int t = threadIdx.x;
        for (int i = t; i < 64 * OUT_CH / 4; i += 256)
            ((float4*)Ws)[i] = ((const float4*)Wout)[i];
        __syncthreads();
    }

    int node = blockIdx.x * 4 + (threadIdx.x >> 6);
    if (node >= N_NODES) return;
    int lane = threadIdx.x & 63;
    int g = lane >> 3;
    int q = lane & 7;
    int deg = cnt[node];
    const int2* erow = ell + (size_t)node * MAXDEG;

    float acc[8] = {0.f, 0.f, 0.f, 0.f, 0.f, 0.f, 0.f, 0.f};
    for (int s = g; s < deg; s += 8) {
        int2  rec = erow[s];
        float nv  = dis[rec.x] * __int_as_float(rec.y);
        fma8_f16(XWh + (size_t)rec.x * 64 + q * 8, nv, acc);
    }
#pragma unroll
    for (int m = 8; m <= 32; m <<= 1)
#pragma unroll
        for (int i = 0; i < 8; ++i)
            acc[i] += __shfl_xor(acc[i], m, 64);

    float dc = dis[node];
    float h[8];
    make_h(acc, XWh + (size_t)node * 64 + q * 8, b, q, dc, h);

    // 64x32 matvec: lane L computes out[L&31] over k-half (L>>5)
    int j    = lane & 31;
    int half = lane >> 5;
    float partial = 0.f;
#pragma unroll
    for (int p = 0; p < 4; ++p) {
        int qp = half * 4 + p;
#pragma unroll
        for (int i = 0; i < 8; ++i) {
            float hv = __shfl(h[i], qp, 64);
            partial = fmaf(hv, Ws[qp * 8 + i][j], partial);
        }
    }
    partial += __shfl_xor(partial, 32, 64);
    if (lane < 32) {
        OUT[(size_t)node * OUT_CH + lane] = tanhf(partial + bout[lane]);
    }
}

// ---------------------------------------------------------------------------
extern "C" void kernel_launch(void* const* d_in, const int* in_sizes, int n_in,
                              void* d_out, int out_size, void* d_ws, size_t ws_size,
                              hipStream_t stream) {
    const float* x     = (const float*)d_in[0];
    const int*   eidx  = (const int*)  d_in[1];
    const float* ew    = (const float*)d_in[2];
    const float* W1    = (const float*)d_in[3];
    const float* b1    = (const float*)d_in[4];
    const float* W2    = (const float*)d_in[5];
    const float* b2    = (const float*)d_in[6];
    const float* Wout  = (const float*)d_in[7];
    const float* bout  = (const float*)d_in[8];
    float*       out   = (float*)d_out;

    const int* row = eidx;             // edge_index[0]
    const int* col = eidx + N_EDGES;   // edge_index[1]

    // workspace layout (~64.8 MB total)
    char*  ws   = (char*)d_ws;
    size_t offs = 0;
    auto alloc = [&](size_t bytes) {
        char* p = ws + offs;
        offs += (bytes + 1023) & ~(size_t)1023;
        return p;
    };
    int*    cnt  = (int*)   alloc((size_t)N_NODES * sizeof(int));
    float*  dis  = (float*) alloc((size_t)N_NODES * sizeof(float));
    int2*   ell  = (int2*)  alloc((size_t)N_NODES * MAXDEG * sizeof(int2));
    __half* xwh1 = (__half*)alloc((size_t)N_NODES * GCN_CH * sizeof(__half));
    __half* xwh2 = (__half*)alloc((size_t)N_NODES * GCN_CH * sizeof(__half));

    const int BLK = 256;
    const int gEdges  = (N_EDGES + BLK - 1) / BLK;
    const int gDis    = (N_NODES + 15) / 16;   // 16 nodes/block (16 lanes each)
    const int gGemm64 = (N_NODES + 15) / 16;   // 16 rows/block
    const int gGather = (N_NODES + 3) / 4;     // 4 nodes/block (1 wave each)

    // ---- graph preprocessing ----
    hipMemsetAsync(cnt, 0, (size_t)N_NODES * sizeof(int), stream);
    fill_ell_kernel<<<gEdges, BLK, 0, stream>>>(row, col, ew, cnt, ell);
    dis_ell_kernel<<<gDis, BLK, 0, stream>>>(cnt, ell, dis);

    // ---- layer 1 GEMM ----
    gemm64_f16_kernel<<<gGemm64, BLK, 0, stream>>>(x, W1, xwh1, N_NODES);

    // ---- layer 1 aggregate + relu + layer 2 GEMM (fused) ----
    gather_mid_kernel<<<gGather, BLK, 0, stream>>>(cnt, ell, xwh1, dis, b1, W2, xwh2);

    // ---- layer 2 aggregate + relu + output projection + tanh (fused) ----
    gather_out_kernel<<<gGather, BLK, 0, stream>>>(cnt, ell, xwh2, dis, b2,
                                                   Wout, bout, out);
}

// Round 8
// 312.755 us; speedup vs baseline: 1.1596x; 1.1596x over previous
//
#include <hip/hip_runtime.h>
#include <hip/hip_fp16.h>
#include <math.h>

#define N_NODES 100000
#define N_EDGES 1600000
#define IN_CH   64
#define GCN_CH  64
#define OUT_CH  32
#define MAXDEG  48   // P(Binomial(1.6M,1e-5) >= 48) ~ 2e-14 per node; guarded in fill

// ---------------------------------------------------------------------------
// 1) ELL fill: cursor atomic IS the histogram. One atomic + one 8B store/edge.
//    ell[c*MAXDEG + k] = (src, edge_weight)   (ell pre-zeroed by memset)
// ---------------------------------------------------------------------------
__global__ void fill_ell_kernel(const int* __restrict__ row, const int* __restrict__ col,
                                const float* __restrict__ ew,
                                int* __restrict__ cnt, int2* __restrict__ ell) {
    int e = blockIdx.x * blockDim.x + threadIdx.x;
    if (e >= N_EDGES) return;
    int r = row[e], c = col[e];
    int k = atomicAdd(&cnt[c], 1);
    if (k < MAXDEG)
        ell[(size_t)c * MAXDEG + k] = make_int2(r, __float_as_int(ew[e]));
}

// ---------------------------------------------------------------------------
// 2) dis[i] = rsqrt(sum of row weights + 1).  16 lanes per node.
// ---------------------------------------------------------------------------
__global__ void dis_ell_kernel(const int* __restrict__ cnt, const int2* __restrict__ ell,
                               float* __restrict__ dis) {
    int t = threadIdx.x;
    int node = blockIdx.x * 16 + (t >> 4);
    if (node >= N_NODES) return;
    int l = t & 15;
    int deg = min(cnt[node], MAXDEG);
    const int2* erow = ell + (size_t)node * MAXDEG;
    float sum = 0.f;
    for (int k = l; k < deg; k += 16)
        sum += __int_as_float(erow[k].y);
    sum += __shfl_xor(sum, 1, 64);
    sum += __shfl_xor(sum, 2, 64);
    sum += __shfl_xor(sum, 4, 64);
    sum += __shfl_xor(sum, 8, 64);
    if (l == 0) dis[node] = rsqrtf(sum + 1.0f);
}

// ---------------------------------------------------------------------------
// 3) norm pass: rec.y <- dis[src] * ew * dis[node]  (full GCN norm, fp32)
//    coalesced read/write of ELL rows; one random dis load per edge (once).
// ---------------------------------------------------------------------------
__global__ void norm_ell_kernel(const int* __restrict__ cnt, int2* __restrict__ ell,
                                const float* __restrict__ dis) {
    int t = threadIdx.x;
    int node = blockIdx.x * 16 + (t >> 4);
    if (node >= N_NODES) return;
    int l = t & 15;
    int deg = min(cnt[node], MAXDEG);
    float dc = dis[node];
    int2* erow = ell + (size_t)node * MAXDEG;
    for (int k = l; k < deg; k += 16) {
        int2 rec = erow[k];
        float nv = dis[rec.x] * __int_as_float(rec.y) * dc;
        erow[k] = make_int2(rec.x, __float_as_int(nv));
    }
}

// ---------------------------------------------------------------------------
// 4a) dense GEMM  Yh[N,64] = fp16( X[N,64] @ W[64,64] ),  X fp32
// ---------------------------------------------------------------------------
__global__ void gemm64_f16_kernel(const float* __restrict__ X, const float* __restrict__ W,
                                  __half* __restrict__ Y, int nrows) {
    __shared__ float4 Ws[64][16];   // Ws[k][q] = W[k][4q..4q+3]
    int t = threadIdx.x;
    for (int i = t; i < 64 * 16; i += 256)
        ((float4*)Ws)[i] = ((const float4*)W)[i];
    __syncthreads();

    int q   = t & 15;
    int sub = t >> 4;               // 16 rows per block
    int row = blockIdx.x * 16 + sub;
    if (row >= nrows) return;
    const float4* xr = (const float4*)(X + (size_t)row * 64);
    float4 acc = {0.f, 0.f, 0.f, 0.f};
#pragma unroll
    for (int k4 = 0; k4 < 16; ++k4) {
        float4 xv = xr[k4];
#pragma unroll
        for (int j = 0; j < 4; ++j) {
            float xs = (j == 0) ? xv.x : (j == 1) ? xv.y : (j == 2) ? xv.z : xv.w;
            float4 wv = Ws[k4 * 4 + j][q];
            acc.x = fmaf(xs, wv.x, acc.x);
            acc.y = fmaf(xs, wv.y, acc.y);
            acc.z = fmaf(xs, wv.z, acc.z);
            acc.w = fmaf(xs, wv.w, acc.w);
        }
    }
    union { __half2 h[2]; float2 f; } u;
    u.h[0] = __floats2half2_rn(acc.x, acc.y);
    u.h[1] = __floats2half2_rn(acc.z, acc.w);
    *(float2*)(Y + (size_t)row * 64 + q * 4) = u.f;
}

// ---------------------------------------------------------------------------
// 4b) dense GEMM, fp16 input:  Yh[N,64] = fp16( Xh[N,64] @ W[64,64] )
// ---------------------------------------------------------------------------
__global__ void gemm64h_f16_kernel(const __half* __restrict__ X, const float* __restrict__ W,
                                   __half* __restrict__ Y, int nrows) {
    __shared__ float4 Ws[64][16];
    int t = threadIdx.x;
    for (int i = t; i < 64 * 16; i += 256)
        ((float4*)Ws)[i] = ((const float4*)W)[i];
    __syncthreads();

    int q   = t & 15;
    int sub = t >> 4;
    int row = blockIdx.x * 16 + sub;
    if (row >= nrows) return;
    const float4* xr = (const float4*)(X + (size_t)row * 64);  // 8 halves per float4
    float4 acc = {0.f, 0.f, 0.f, 0.f};
#pragma unroll
    for (int k8 = 0; k8 < 8; ++k8) {
        float4 raw = xr[k8];
        const __half2* hp = (const __half2*)&raw;
#pragma unroll
        for (int j = 0; j < 4; ++j) {
            float xs0 = __low2float(hp[j]);
            float xs1 = __high2float(hp[j]);
            float4 w0 = Ws[k8 * 8 + 2 * j][q];
            float4 w1 = Ws[k8 * 8 + 2 * j + 1][q];
            acc.x = fmaf(xs0, w0.x, acc.x); acc.y = fmaf(xs0, w0.y, acc.y);
            acc.z = fmaf(xs0, w0.z, acc.z); acc.w = fmaf(xs0, w0.w, acc.w);
            acc.x = fmaf(xs1, w1.x, acc.x); acc.y = fmaf(xs1, w1.y, acc.y);
            acc.z = fmaf(xs1, w1.z, acc.z); acc.w = fmaf(xs1, w1.w, acc.w);
        }
    }
    union { __half2 h[2]; float2 f; } u;
    u.h[0] = __floats2half2_rn(acc.x, acc.y);
    u.h[1] = __floats2half2_rn(acc.z, acc.w);
    *(float2*)(Y + (size_t)row * 64 + q * 4) = u.f;
}

// ---------------------------------------------------------------------------
// helper: load 8 fp16 channels (16 B) and fma into 8 fp32 accumulators
// ---------------------------------------------------------------------------
__device__ inline void fma8_f16(const __half* p, float nv, float* acc) {
    float4 raw = *(const float4*)p;
    const __half2* hp = (const __half2*)&raw;
#pragma unroll
    for (int i = 0; i < 4; ++i) {
        acc[2 * i + 0] = fmaf(nv, __low2float(hp[i]),  acc[2 * i + 0]);
        acc[2 * i + 1] = fmaf(nv, __high2float(hp[i]), acc[2 * i + 1]);
    }
}

// helper: epilogue — h[i] = relu(acc[i] + dd*x_self[i] + b[i]),  dd = dis^2
__device__ inline void make_h(const float* acc, const __half* xself_p,
                              const float* b, int q, float dd, float* h) {
    float4 raw = *(const float4*)xself_p;
    const __half2* hp = (const __half2*)&raw;
    float4 b0 = *(const float4*)(b + q * 8);
    float4 b1 = *(const float4*)(b + q * 8 + 4);
    float xs[8] = {__low2float(hp[0]), __high2float(hp[0]),
                   __low2float(hp[1]), __high2float(hp[1]),
                   __low2float(hp[2]), __high2float(hp[2]),
                   __low2float(hp[3]), __high2float(hp[3])};
    float bb[8] = {b0.x, b0.y, b0.z, b0.w, b1.x, b1.y, b1.z, b1.w};
#pragma unroll
    for (int i = 0; i < 8; ++i)
        h[i] = fmaxf(fmaf(dd, xs[i], acc[i]) + bb[i], 0.f);
}

// ---------------------------------------------------------------------------
// 5) gather_h: register-staged edge records.
//    One wave per node; lane = (edge-group g = lane>>3) x (channel-oct q = lane&7).
//    myrec = erow[lane] (ONE coalesced load, deg<=48<64, zero-padded rows),
//    loop gets (src,nv) via shfl -> XW gathers issue with no record wait.
//    H stored fp16.
// ---------------------------------------------------------------------------
__global__ void gather_h_kernel(const int* __restrict__ cnt, const int2* __restrict__ ell,
                                const __half* __restrict__ XWh,
                                const float* __restrict__ dis, const float* __restrict__ b,
                                __half* __restrict__ H) {
    int node = blockIdx.x * (blockDim.x >> 6) + (threadIdx.x >> 6);
    if (node >= N_NODES) return;
    int lane = threadIdx.x & 63;
    int g = lane >> 3;          // edge group 0..7
    int q = lane & 7;           // channel oct
    const int2* erow = ell + (size_t)node * MAXDEG;
    int2 myrec = (lane < MAXDEG) ? erow[lane] : make_int2(0, 0);
    int deg = min(cnt[node], MAXDEG);

    float acc[8] = {0.f, 0.f, 0.f, 0.f, 0.f, 0.f, 0.f, 0.f};
    for (int s = 0; s < deg; s += 8) {
        int   src = __shfl(myrec.x, s + g, 64);
        float nv  = __shfl(__int_as_float(myrec.y), s + g, 64);
        fma8_f16(XWh + (size_t)src * 64 + q * 8, nv, acc);
    }
#pragma unroll
    for (int m = 8; m <= 32; m <<= 1)
#pragma unroll
        for (int i = 0; i < 8; ++i)
            acc[i] += __shfl_xor(acc[i], m, 64);

    if (g == 0) {
        float dc = dis[node];
        float h[8];
        make_h(acc, XWh + (size_t)node * 64 + q * 8, b, q, dc * dc, h);
        union { __half2 hh[4]; float4 f; } u;
        u.hh[0] = __floats2half2_rn(h[0], h[1]);
        u.hh[1] = __floats2half2_rn(h[2], h[3]);
        u.hh[2] = __floats2half2_rn(h[4], h[5]);
        u.hh[3] = __floats2half2_rn(h[6], h[7]);
        *(float4*)(H + (size_t)node * 64 + q * 8) = u.f;
    }
}

// ---------------------------------------------------------------------------
// 6) gather_out: same register-staged loop on XW2h, then fused
//    tanh(h2 @ Wout + bout) via 32-wide shfl matvec.
// ---------------------------------------------------------------------------
__global__ void gather_out_kernel(const int* __restrict__ cnt, const int2* __restrict__ ell,
                                  const __half* __restrict__ XWh,
                                  const float* __restrict__ dis, const float* __restrict__ b,
                                  const float* __restrict__ Wout, const float* __restrict__ bout,
                                  float* __restrict__ OUT) {
    __shared__ float Ws[64][OUT_CH];          // Wout[k][j], 8 KB
    {
        int t = threadIdx.x;
        for (int i = t; i < 64 * OUT_CH / 4; i += (int)blockDim.x)
            ((float4*)Ws)[i] = ((const float4*)Wout)[i];
        __syncthreads();
    }

    int node = blockIdx.x * (blockDim.x >> 6) + (threadIdx.x >> 6);
    if (node >= N_NODES) return;
    int lane = threadIdx.x & 63;
    int g = lane >> 3;
    int q = lane & 7;
    const int2* erow = ell + (size_t)node * MAXDEG;
    int2 myrec = (lane < MAXDEG) ? erow[lane] : make_int2(0, 0);
    int deg = min(cnt[node], MAXDEG);

    float acc[8] = {0.f, 0.f, 0.f, 0.f, 0.f, 0.f, 0.f, 0.f};
    for (int s = 0; s < deg; s += 8) {
        int   src = __shfl(myrec.x, s + g, 64);
        float nv  = __shfl(__int_as_float(myrec.y), s + g, 64);
        fma8_f16(XWh + (size_t)src * 64 + q * 8, nv, acc);
    }
#pragma unroll
    for (int m = 8; m <= 32; m <<= 1)
#pragma unroll
        for (int i = 0; i < 8; ++i)
            acc[i] += __shfl_xor(acc[i], m, 64);

    float dc = dis[node];
    float h[8];
    make_h(acc, XWh + (size_t)node * 64 + q * 8, b, q, dc * dc, h);

    // 64x32 matvec: lane L computes out[L&31] over k-half (L>>5)
    int j    = lane & 31;
    int half = lane >> 5;
    float partial = 0.f;
#pragma unroll
    for (int p = 0; p < 4; ++p) {
        int qp = half * 4 + p;
#pragma unroll
        for (int i = 0; i < 8; ++i) {
            float hv = __shfl(h[i], qp, 64);
            partial = fmaf(hv, Ws[qp * 8 + i][j], partial);
        }
    }
    partial += __shfl_xor(partial, 32, 64);
    if (lane < 32) {
        OUT[(size_t)node * OUT_CH + lane] = tanhf(partial + bout[lane]);
    }
}

// ---------------------------------------------------------------------------
extern "C" void kernel_launch(void* const* d_in, const int* in_sizes, int n_in,
                              void* d_out, int out_size, void* d_ws, size_t ws_size,
                              hipStream_t stream) {
    const float* x     = (const float*)d_in[0];
    const int*   eidx  = (const int*)  d_in[1];
    const float* ew    = (const float*)d_in[2];
    const float* W1    = (const float*)d_in[3];
    const float* b1    = (const float*)d_in[4];
    const float* W2    = (const float*)d_in[5];
    const float* b2    = (const float*)d_in[6];
    const float* Wout  = (const float*)d_in[7];
    const float* bout  = (const float*)d_in[8];
    float*       out   = (float*)d_out;

    const int* row = eidx;             // edge_index[0]
    const int* col = eidx + N_EDGES;   // edge_index[1]

    // workspace layout (~64.8 MB, same budget as round 6/7)
    char*  ws   = (char*)d_ws;
    size_t offs = 0;
    auto alloc = [&](size_t bytes) {
        char* p = ws + offs;
        offs += (bytes + 1023) & ~(size_t)1023;
        return p;
    };
    int*    cnt  = (int*)   alloc((size_t)N_NODES * sizeof(int));
    float*  dis  = (float*) alloc((size_t)N_NODES * sizeof(float));
    int2*   ell  = (int2*)  alloc((size_t)N_NODES * MAXDEG * sizeof(int2));
    __half* xwh  = (__half*)alloc((size_t)N_NODES * GCN_CH * sizeof(__half)); // xw1, later xw2
    __half* hbuf = (__half*)alloc((size_t)N_NODES * GCN_CH * sizeof(__half)); // H (fp16)

    const int BLK  = 256;
    const int BLKG = 512;                           // 8 nodes per gather block
    const int gEdges  = (N_EDGES + BLK - 1) / BLK;
    const int gNode16 = (N_NODES + 15) / 16;        // 16 nodes/block (16 lanes each)
    const int gGemm64 = (N_NODES + 15) / 16;        // 16 rows/block
    const int gGather = (N_NODES + 7) / 8;          // 8 nodes/block (1 wave each)

    // ---- graph preprocessing ----
    hipMemsetAsync(cnt, 0, (size_t)N_NODES * sizeof(int), stream);
    hipMemsetAsync(ell, 0, (size_t)N_NODES * MAXDEG * sizeof(int2), stream);
    fill_ell_kernel<<<gEdges, BLK, 0, stream>>>(row, col, ew, cnt, ell);
    dis_ell_kernel<<<gNode16, BLK, 0, stream>>>(cnt, ell, dis);
    norm_ell_kernel<<<gNode16, BLK, 0, stream>>>(cnt, ell, dis);

    // ---- layer 1: GEMM + aggregate/relu -> H (fp16) ----
    gemm64_f16_kernel<<<gGemm64, BLK, 0, stream>>>(x, W1, xwh, N_NODES);
    gather_h_kernel<<<gGather, BLKG, 0, stream>>>(cnt, ell, xwh, dis, b1, hbuf);

    // ---- layer 2: GEMM (H fp16 @ W2 -> xwh reused) + aggregate/out fused ----
    gemm64h_f16_kernel<<<gGemm64, BLK, 0, stream>>>(hbuf, W2, xwh, N_NODES);
    gather_out_kernel<<<gGather, BLKG, 0, stream>>>(cnt, ell, xwh, dis, b2,
                                                    Wout, bout, out);
}